// Round 6
// baseline (267.316 us; speedup 1.0000x reference)
//
#include <hip/hip_runtime.h>

#define B_ 8
#define N_ 4096
#define O_ 64
#define KL 40
#define KS 20
#define EPSV 1e-5
#define SLOPE 0.2f

typedef unsigned long long u64;
typedef unsigned int u32;

__device__ __forceinline__ float leaky(float v) { return v >= 0.f ? v : SLOPE * v; }

// map float -> u32, smaller mapped value == larger float (total order, desc)
__device__ __forceinline__ u32 fmap(float d) {
    const u32 u = __float_as_uint(d);
    return ((int)u < 0) ? u : (0x7FFFFFFFu - u);
}

// dual ascending bitonic sort of two independent 64-key sets (ILP x2)
__device__ __forceinline__ void sort64_pair(u64& a, u64& e, int lane) {
#pragma unroll
    for (int k = 2; k <= 64; k <<= 1) {
#pragma unroll
        for (int s = k >> 1; s > 0; s >>= 1) {
            const u64 oa = __shfl_xor(a, s);
            const u64 oe = __shfl_xor(e, s);
            const bool dirUp = ((lane & k) == 0);
            const bool lower = ((lane & s) == 0);
            const bool sel = (dirUp == lower);
            a = ((a < oa) == sel) ? a : oa;
            e = ((e < oe) == sel) ? e : oe;
        }
    }
}

// L ascending; basc ascending. keep 64 smallest of the 128-union, ascending.
__device__ __forceinline__ u64 merge64(u64 L, u64 basc, int lane) {
    const u64 bd = __shfl_xor(basc, 63);        // reverse -> descending
    L = (L < bd) ? L : bd;                       // valley min -> bitonic
#pragma unroll
    for (int s = 32; s > 0; s >>= 1) {
        const u64 ok = __shfl_xor(L, s);
        const bool lower = ((lane & s) == 0);
        L = ((L < ok) == lower) ? L : ok;
    }
    return L;
}

// ---------------- K1: KNN (2 queries/wave, 1K-pt tiles, joint dual flush) --------
__global__ __launch_bounds__(512, 8) void knn_kernel(const float* __restrict__ x,
                                                     const float* __restrict__ w_s,
                                                     const float* __restrict__ w_l,
                                                     int* __restrict__ idx_out,
                                                     float* __restrict__ A_s,
                                                     float* __restrict__ C_s,
                                                     float* __restrict__ A_l,
                                                     float* __restrict__ C_l) {
    __shared__ float4 xt[1024];         // 16 KB point tile (x,y,z,xx)
    __shared__ u64 buf[8][2][128];      // 16 KB candidate buffers
    const int sbid = ((blockIdx.x & 7) << 8) + (blockIdx.x >> 3);  // XCD: 1 batch/XCD
    const int b = sbid >> 8;
    const int n0 = (sbid & 255) << 4;   // 16 queries per block
    const float* xb = x + (size_t)b * 3 * N_;
    const int tid = threadIdx.x;
    const int wave = tid >> 6, lane = tid & 63;
    const int i0 = n0 + wave * 2;

    float4 q0, q1;
    {
        const float ax = xb[i0],     ay = xb[N_ + i0],     az = xb[2 * N_ + i0];
        const float ex = xb[i0 + 1], ey = xb[N_ + i0 + 1], ez = xb[2 * N_ + i0 + 1];
        q0 = make_float4(ax, ay, az, ax * ax + ay * ay + az * az);
        q1 = make_float4(ex, ey, ez, ex * ex + ey * ey + ez * ez);
    }
    const float nw0 = -q0.w, nw1 = -q1.w;
    u64 L0 = ~0ull, L1 = ~0ull;
    u32 th0 = 0xFFFFFFFFu, th1 = 0xFFFFFFFFu;
    int cnt0 = 0, cnt1 = 0;

    for (int tile = 0; tile < 4; ++tile) {
        const int tbase = tile << 10;
        __syncthreads();
        for (int t = tid; t < 1024; t += 512) {
            const int g = tbase + t;
            const float cx = xb[g], cy = xb[N_ + g], cz = xb[2 * N_ + g];
            xt[t] = make_float4(cx, cy, cz, cx * cx + cy * cy + cz * cz);
        }
        __syncthreads();
#pragma unroll 2
        for (int it = 0; it < 16; ++it) {
            const int jj = (it << 6) + lane;
            const float4 c = xt[jj];
            const int j = tbase + jj;
            const float dot0 = q0.x * c.x + q0.y * c.y + q0.z * c.z;
            const float dot1 = q1.x * c.x + q1.y * c.y + q1.z * c.z;
            const float d0 = fmaf(dot0, 2.f, nw0) - c.w;   // == 2*dot - xxq - xxj
            const float d1 = fmaf(dot1, 2.f, nw1) - c.w;
            const u32 k0 = fmap(d0), k1 = fmap(d1);
            const bool p0 = (k0 <= th0), p1 = (k1 <= th1);
            const u64 m0 = __ballot(p0), m1 = __ballot(p1);
            if (m0) {
                const int pos = cnt0 + __builtin_amdgcn_mbcnt_hi(
                    (u32)(m0 >> 32), __builtin_amdgcn_mbcnt_lo((u32)m0, 0));
                if (p0) buf[wave][0][pos] = ((u64)k0 << 32) | (u32)j;
                cnt0 += __popcll(m0);
            }
            if (m1) {
                const int pos = cnt1 + __builtin_amdgcn_mbcnt_hi(
                    (u32)(m1 >> 32), __builtin_amdgcn_mbcnt_lo((u32)m1, 0));
                if (p1) buf[wave][1][pos] = ((u64)k1 << 32) | (u32)j;
                cnt1 += __popcll(m1);
            }
            if ((cnt0 | cnt1) >= 64) {        // joint flush, dual sort chains
                const int t0 = min(cnt0, 64), t1 = min(cnt1, 64);
                u64 a = (lane < t0) ? buf[wave][0][cnt0 - t0 + lane] : ~0ull;
                u64 e = (lane < t1) ? buf[wave][1][cnt1 - t1 + lane] : ~0ull;
                sort64_pair(a, e, lane);
                L0 = merge64(L0, a, lane);
                L1 = merge64(L1, e, lane);
                th0 = __shfl((u32)(L0 >> 32), KL - 1);
                th1 = __shfl((u32)(L1 >> 32), KL - 1);
                cnt0 -= t0; cnt1 -= t1;
            }
        }
    }
    if ((cnt0 | cnt1) > 0) {                  // leftovers (< 64 each)
        u64 a = (lane < cnt0) ? buf[wave][0][lane] : ~0ull;
        u64 e = (lane < cnt1) ? buf[wave][1][lane] : ~0ull;
        sort64_pair(a, e, lane);
        L0 = merge64(L0, a, lane);
        L1 = merge64(L1, e, lane);
    }
    if (lane < KL) {
        idx_out[(size_t)((b << 12) + i0) * KL + lane]     = (int)(u32)L0;
        idx_out[(size_t)((b << 12) + i0 + 1) * KL + lane] = (int)(u32)L1;
    }
    // ---- proj epilogue for this block's 16 points ----
    for (int t = tid; t < 16 * 64; t += 512) {
        const int nl = t >> 6, o = t & 63;
        const int n = n0 + nl;
        const float px = xb[n], py = xb[N_ + n], pz = xb[2 * N_ + n];
        const float* ws6 = w_s + o * 6;
        const float* wl6 = w_l + o * 6;
        const size_t gid = (size_t)((b << 12) + n) * 64 + o;
        A_s[gid] = ws6[0] * px + ws6[1] * py + ws6[2] * pz;
        C_s[gid] = (ws6[3] - ws6[0]) * px + (ws6[4] - ws6[1]) * py + (ws6[5] - ws6[2]) * pz;
        A_l[gid] = wl6[0] * px + wl6[1] * py + wl6[2] * pz;
        C_l[gid] = (wl6[3] - wl6[0]) * px + (wl6[4] - wl6[1]) * py + (wl6[5] - wl6[2]) * pz;
    }
}

// ---------------- K3: gather neighbors, per-(b,n) max/min + BN stat partials -----
__global__ __launch_bounds__(256) void gather_kernel(const int* __restrict__ idx,
    const float* __restrict__ A_s, const float* __restrict__ C_s,
    const float* __restrict__ A_l, const float* __restrict__ C_l,
    float* __restrict__ max_s, float* __restrict__ min_s,
    float* __restrict__ max_l, float* __restrict__ min_l,
    float* __restrict__ partial1) {
    const int tid = threadIdx.x;
    const int wave = tid >> 6, lane = tid & 63;
    const int sbid = ((blockIdx.x & 7) << 10) + (blockIdx.x >> 3);  // 1 batch/XCD
    const int bn = sbid * 4 + wave;
    const int b = bn >> 12;
    const int jb = b << 12;
    const int* ip = idx + (size_t)bn * KL;
    const float cs = C_s[(size_t)bn * 64 + lane];
    const float cl = C_l[(size_t)bn * 64 + lane];
    float mxs = -INFINITY, mns = INFINITY, mxl = -INFINITY, mnl = INFINITY;
    float sums = 0.f, sss = 0.f, suml = 0.f, ssl = 0.f;
#pragma unroll
    for (int k = 0; k < KL; ++k) {
        const int j = ip[k];
        const float hl = A_l[(size_t)(jb + j) * 64 + lane] + cl;
        mxl = fmaxf(mxl, hl); mnl = fminf(mnl, hl);
        suml += hl; ssl = fmaf(hl, hl, ssl);
        if (k < KS) {
            const float hs = A_s[(size_t)(jb + j) * 64 + lane] + cs;
            mxs = fmaxf(mxs, hs); mns = fminf(mns, hs);
            sums += hs; sss = fmaf(hs, hs, sss);
        }
    }
    max_s[(size_t)bn * 64 + lane] = mxs; min_s[(size_t)bn * 64 + lane] = mns;
    max_l[(size_t)bn * 64 + lane] = mxl; min_l[(size_t)bn * 64 + lane] = mnl;
    __shared__ float red[4][4][64];
    red[0][wave][lane] = sums; red[1][wave][lane] = sss;
    red[2][wave][lane] = suml; red[3][wave][lane] = ssl;
    __syncthreads();
    const int st = tid >> 6;
    const int o = tid & 63;
    partial1[(size_t)blockIdx.x * 256 + tid] =
        red[st][0][o] + red[st][1][o] + red[st][2][o] + red[st][3][o];
}

// ---------------- K4a/K4b: reduce edge-conv BN stats -> scale/bias ---------------
__global__ void reduce1a_kernel(const float* __restrict__ partial1, double* __restrict__ partialD1) {
    const int t = threadIdx.x;   // 256
    double acc = 0.0;
    const int r0 = blockIdx.x * 64;   // 128 blocks
    for (int r = 0; r < 64; ++r) acc += (double)partial1[(size_t)(r0 + r) * 256 + t];
    partialD1[(size_t)blockIdx.x * 256 + t] = acc;
}

__global__ void reduce1b_kernel(const double* __restrict__ partialD1,
                                const float* __restrict__ g_s, const float* __restrict__ b_s,
                                const float* __restrict__ g_l, const float* __restrict__ b_l,
                                float* __restrict__ sb1) {
    const int t = threadIdx.x;   // 256
    double acc = 0.0;
    for (int r = 0; r < 128; ++r) acc += partialD1[(size_t)r * 256 + t];
    __shared__ double sums[256];
    sums[t] = acc;
    __syncthreads();
    if (t < 64) {
        const double ns = (double)B_ * N_ * KS;
        const double nl = (double)B_ * N_ * KL;
        double mu = sums[t] / ns;
        double var = sums[64 + t] / ns - mu * mu;
        double sc = (double)g_s[t] / sqrt(var + EPSV);
        sb1[t] = (float)sc;
        sb1[64 + t] = (float)((double)b_s[t] - mu * sc);
        mu = sums[128 + t] / nl;
        var = sums[192 + t] / nl - mu * mu;
        sc = (double)g_l[t] / sqrt(var + EPSV);
        sb1[128 + t] = (float)sc;
        sb1[192 + t] = (float)((double)b_l[t] - mu * sc);
    }
}

// ---------------- K5: BN+leaky on maxes, 64x128 fuse matvec, stats ---------------
__global__ __launch_bounds__(256) void fuse_kernel(
    const float* __restrict__ max_s, const float* __restrict__ min_s,
    const float* __restrict__ max_l, const float* __restrict__ min_l,
    const float* __restrict__ sb1, const float* __restrict__ w_f,
    float* __restrict__ f_buf, float* __restrict__ partial2) {
    __shared__ float wfT[128 * 64];   // transposed: wfT[c][o]
    __shared__ float av[4][128];
    __shared__ float red[2][4][64];
    const int tid = threadIdx.x;
    for (int t = tid; t < 8192; t += 256) {
        const int c = t >> 6, o = t & 63;
        wfT[t] = w_f[o * 128 + c];
    }
    const int sbid = ((blockIdx.x & 7) << 8) + (blockIdx.x >> 3);   // 1 batch/XCD
    const int wave = tid >> 6, lane = tid & 63;
    const float sc_s = sb1[lane], bi_s = sb1[64 + lane];
    const float sc_l = sb1[128 + lane], bi_l = sb1[192 + lane];
    float sum_f = 0.f, ss_f = 0.f;
    __syncthreads();
    for (int p = 0; p < 4; ++p) {
        const int bn = (sbid * 4 + wave) * 4 + p;   // 2048 blocks
        const size_t base = (size_t)bn * 64 + lane;
        const float hs = sc_s >= 0.f ? max_s[base] : min_s[base];
        const float a_s = leaky(fmaf(sc_s, hs, bi_s));
        const float hl = sc_l >= 0.f ? max_l[base] : min_l[base];
        const float a_l = leaky(fmaf(sc_l, hl, bi_l));
        av[wave][lane] = a_s;
        av[wave][64 + lane] = a_l;     // per-wave buffer: no block barrier needed
        float acc = 0.f;
#pragma unroll
        for (int c = 0; c < 128; ++c) acc = fmaf(wfT[c * 64 + lane], av[wave][c], acc);
        f_buf[base] = acc;
        sum_f += acc;
        ss_f = fmaf(acc, acc, ss_f);
    }
    red[0][wave][lane] = sum_f;
    red[1][wave][lane] = ss_f;
    __syncthreads();
    if (tid < 128) {
        const int st = tid >> 6, o = tid & 63;
        partial2[(size_t)blockIdx.x * 128 + tid] =
            red[st][0][o] + red[st][1][o] + red[st][2][o] + red[st][3][o];
    }
}

// ---------------- K6a/K6b: reduce final BN stats ---------------------------------
__global__ void reduce2a_kernel(const float* __restrict__ partial2, double* __restrict__ partialD2) {
    const int t = threadIdx.x;   // 128
    double acc = 0.0;
    const int r0 = blockIdx.x * 32;   // 64 blocks
    for (int r = 0; r < 32; ++r) acc += (double)partial2[(size_t)(r0 + r) * 128 + t];
    partialD2[(size_t)blockIdx.x * 128 + t] = acc;
}

__global__ void reduce2b_kernel(const double* __restrict__ partialD2,
                                const float* __restrict__ g_f, const float* __restrict__ b_f,
                                float* __restrict__ sb2) {
    const int t = threadIdx.x;   // 128
    double acc = 0.0;
    for (int r = 0; r < 64; ++r) acc += partialD2[(size_t)r * 128 + t];
    __shared__ double sums[128];
    sums[t] = acc;
    __syncthreads();
    if (t < 64) {
        const double n = (double)B_ * N_;
        const double mu = sums[t] / n;
        const double var = sums[64 + t] / n - mu * mu;
        const double sc = (double)g_f[t] / sqrt(var + EPSV);
        sb2[t] = (float)sc;
        sb2[64 + t] = (float)((double)b_f[t] - mu * sc);
    }
}

// ---------------- K7: final BN+leaky + transpose to [B,O,N] ----------------------
__global__ __launch_bounds__(256) void final_kernel(const float* __restrict__ f_buf,
                                                    const float* __restrict__ sb2,
                                                    float* __restrict__ out) {
    __shared__ float tile[64][65];
    const int sbid = ((blockIdx.x & 7) << 6) + (blockIdx.x >> 3);   // 1 batch/XCD
    const int b = sbid >> 6;                 // 512 blocks
    const int n0 = (sbid & 63) << 6;
#pragma unroll
    for (int r = 0; r < 16; ++r) {
        const int t = r * 256 + threadIdx.x;
        const int n = t >> 6, o = t & 63;
        const float v = f_buf[(size_t)((b << 12) + n0 + n) * 64 + o];
        const float h = fmaf(sb2[o], v, sb2[64 + o]);
        tile[n][o] = leaky(h);
    }
    __syncthreads();
#pragma unroll
    for (int r = 0; r < 16; ++r) {
        const int t = r * 256 + threadIdx.x;
        const int o = t >> 6, n = t & 63;
        out[(size_t)((b << 6) + o) * N_ + n0 + n] = tile[n][o];
    }
}

// ---------------- launch ---------------------------------------------------------
extern "C" void kernel_launch(void* const* d_in, const int* in_sizes, int n_in,
                              void* d_out, int out_size, void* d_ws, size_t ws_size,
                              hipStream_t stream) {
    (void)in_sizes; (void)n_in; (void)out_size; (void)ws_size;
    const float* x   = (const float*)d_in[0];
    const float* w_s = (const float*)d_in[1];
    const float* g_s = (const float*)d_in[2];
    const float* b_s = (const float*)d_in[3];
    const float* w_l = (const float*)d_in[4];
    const float* g_l = (const float*)d_in[5];
    const float* b_l = (const float*)d_in[6];
    const float* w_f = (const float*)d_in[7];
    const float* g_f = (const float*)d_in[8];
    const float* b_f = (const float*)d_in[9];
    float* out = (float*)d_out;
    char* ws = (char*)d_ws;

    constexpr size_t SZ_PT   = (size_t)B_ * N_ * 64 * 4;      // 8,388,608
    constexpr size_t OFF_IDX = 0;
    constexpr size_t OFF_AS  = OFF_IDX + (size_t)B_ * N_ * KL * 4;
    constexpr size_t OFF_CS  = OFF_AS + SZ_PT;
    constexpr size_t OFF_AL  = OFF_CS + SZ_PT;
    constexpr size_t OFF_CL  = OFF_AL + SZ_PT;
    constexpr size_t OFF_MXS = OFF_CL + SZ_PT;
    constexpr size_t OFF_MNS = OFF_MXS + SZ_PT;
    constexpr size_t OFF_MXL = OFF_MNS + SZ_PT;
    constexpr size_t OFF_MNL = OFF_MXL + SZ_PT;
    constexpr size_t OFF_P1  = OFF_MNL + SZ_PT;
    constexpr size_t OFF_PD1 = OFF_P1 + (size_t)8192 * 256 * 4;
    constexpr size_t OFF_SB1 = OFF_PD1 + (size_t)128 * 256 * 8;
    constexpr size_t OFF_F   = OFF_SB1 + 1024;
    constexpr size_t OFF_P2  = OFF_F + SZ_PT;
    constexpr size_t OFF_PD2 = OFF_P2 + (size_t)2048 * 128 * 4;
    constexpr size_t OFF_SB2 = OFF_PD2 + (size_t)64 * 128 * 8;

    int*    idx  = (int*)(ws + OFF_IDX);
    float*  A_s  = (float*)(ws + OFF_AS);
    float*  C_s  = (float*)(ws + OFF_CS);
    float*  A_l  = (float*)(ws + OFF_AL);
    float*  C_l  = (float*)(ws + OFF_CL);
    float*  mxs  = (float*)(ws + OFF_MXS);
    float*  mns  = (float*)(ws + OFF_MNS);
    float*  mxl  = (float*)(ws + OFF_MXL);
    float*  mnl  = (float*)(ws + OFF_MNL);
    float*  p1   = (float*)(ws + OFF_P1);
    double* pd1  = (double*)(ws + OFF_PD1);
    float*  sb1  = (float*)(ws + OFF_SB1);
    float*  fb   = (float*)(ws + OFF_F);
    float*  p2   = (float*)(ws + OFF_P2);
    double* pd2  = (double*)(ws + OFF_PD2);
    float*  sb2  = (float*)(ws + OFF_SB2);

    hipLaunchKernelGGL(knn_kernel, dim3(2048), dim3(512), 0, stream,
                       x, w_s, w_l, idx, A_s, C_s, A_l, C_l);
    hipLaunchKernelGGL(gather_kernel, dim3(8192), dim3(256), 0, stream,
                       idx, A_s, C_s, A_l, C_l, mxs, mns, mxl, mnl, p1);
    hipLaunchKernelGGL(reduce1a_kernel, dim3(128), dim3(256), 0, stream, p1, pd1);
    hipLaunchKernelGGL(reduce1b_kernel, dim3(1), dim3(256), 0, stream, pd1, g_s, b_s, g_l, b_l, sb1);
    hipLaunchKernelGGL(fuse_kernel, dim3(2048), dim3(256), 0, stream,
                       mxs, mns, mxl, mnl, sb1, w_f, fb, p2);
    hipLaunchKernelGGL(reduce2a_kernel, dim3(64), dim3(128), 0, stream, p2, pd2);
    hipLaunchKernelGGL(reduce2b_kernel, dim3(1), dim3(128), 0, stream, pd2, g_f, b_f, sb2);
    hipLaunchKernelGGL(final_kernel, dim3(512), dim3(256), 0, stream, fb, sb2, out);
}

// Round 7
// 220.386 us; speedup vs baseline: 1.2129x; 1.2129x over previous
//
#include <hip/hip_runtime.h>

#define B_ 8
#define N_ 4096
#define O_ 64
#define KL 40
#define KS 20
#define EPSV 1e-5
#define SLOPE 0.2f

typedef unsigned long long u64;
typedef unsigned int u32;

__device__ __forceinline__ float leaky(float v) { return v >= 0.f ? v : SLOPE * v; }

// map float -> u32, smaller mapped value == larger float (total order, desc)
__device__ __forceinline__ u32 fmap(float d) {
    const u32 u = __float_as_uint(d);
    return ((int)u < 0) ? u : (0x7FFFFFFFu - u);
}

// lane exchange by XOR stride S. S=1,2,8 run on the VALU via DPP (no DS-pipe);
// S=4,16,32,63 fall back to ds-based shfl. Exchange transport only — the
// surrounding compare/select network is unchanged.
template <int S>
__device__ __forceinline__ u64 xor_ex64(u64 v) {
    if constexpr (S == 1 || S == 2 || S == 8) {
        constexpr int CTRL = (S == 1) ? 0xB1 : (S == 2) ? 0x4E : 0x128;
        const int lo = __builtin_amdgcn_update_dpp(0, (int)(u32)v, CTRL, 0xF, 0xF, true);
        const int hi = __builtin_amdgcn_update_dpp(0, (int)(u32)(v >> 32), CTRL, 0xF, 0xF, true);
        return ((u64)(u32)hi << 32) | (u32)lo;
    } else {
        return __shfl_xor(v, S);
    }
}

// one bitonic stage (level K, stride S) applied to two independent keys (ILP x2)
template <int K, int S>
__device__ __forceinline__ void stage_pair(u64& a, u64& e, int lane) {
    const u64 oa = xor_ex64<S>(a);
    const u64 oe = xor_ex64<S>(e);
    const bool sel = (((lane & K) == 0) == ((lane & S) == 0));
    a = ((a < oa) == sel) ? a : oa;
    e = ((e < oe) == sel) ? e : oe;
}

// dual ascending bitonic sort of two independent 64-key sets
__device__ __forceinline__ void sort64_pair(u64& a, u64& e, int lane) {
    stage_pair<2, 1>(a, e, lane);
    stage_pair<4, 2>(a, e, lane);   stage_pair<4, 1>(a, e, lane);
    stage_pair<8, 4>(a, e, lane);   stage_pair<8, 2>(a, e, lane);   stage_pair<8, 1>(a, e, lane);
    stage_pair<16, 8>(a, e, lane);  stage_pair<16, 4>(a, e, lane);  stage_pair<16, 2>(a, e, lane);  stage_pair<16, 1>(a, e, lane);
    stage_pair<32, 16>(a, e, lane); stage_pair<32, 8>(a, e, lane);  stage_pair<32, 4>(a, e, lane);  stage_pair<32, 2>(a, e, lane);  stage_pair<32, 1>(a, e, lane);
    stage_pair<64, 32>(a, e, lane); stage_pair<64, 16>(a, e, lane); stage_pair<64, 8>(a, e, lane);  stage_pair<64, 4>(a, e, lane);  stage_pair<64, 2>(a, e, lane);  stage_pair<64, 1>(a, e, lane);
}

// L0/L1 ascending lists; a/e ascending buffers. keep 64 smallest of each union.
__device__ __forceinline__ void merge_pair(u64& L0, u64& L1, u64 a, u64 e, int lane) {
    const u64 ra = __shfl_xor(a, 63);            // reverse -> descending
    const u64 re = __shfl_xor(e, 63);
    L0 = (L0 < ra) ? L0 : ra;                    // valley min -> bitonic
    L1 = (L1 < re) ? L1 : re;
    stage_pair<0, 32>(L0, L1, lane);             // K=0 -> pure descending cleanup
    stage_pair<0, 16>(L0, L1, lane);
    stage_pair<0, 8>(L0, L1, lane);
    stage_pair<0, 4>(L0, L1, lane);
    stage_pair<0, 2>(L0, L1, lane);
    stage_pair<0, 1>(L0, L1, lane);
}

// ---------------- K1: KNN (2 queries/wave, 1K-pt tiles, joint dual flush) --------
__global__ __launch_bounds__(512, 8) void knn_kernel(const float* __restrict__ x,
                                                     const float* __restrict__ w_s,
                                                     const float* __restrict__ w_l,
                                                     int* __restrict__ idx_out,
                                                     float* __restrict__ A_s,
                                                     float* __restrict__ C_s,
                                                     float* __restrict__ A_l,
                                                     float* __restrict__ C_l) {
    __shared__ float4 xt[1024];         // 16 KB point tile (x,y,z,xx)
    __shared__ u64 buf[8][2][128];      // 16 KB candidate buffers
    const int sbid = ((blockIdx.x & 7) << 8) + (blockIdx.x >> 3);  // XCD: 1 batch/XCD
    const int b = sbid >> 8;
    const int n0 = (sbid & 255) << 4;   // 16 queries per block
    const float* xb = x + (size_t)b * 3 * N_;
    const int tid = threadIdx.x;
    const int wave = tid >> 6, lane = tid & 63;
    const int i0 = n0 + wave * 2;

    float4 q0, q1;
    {
        const float ax = xb[i0],     ay = xb[N_ + i0],     az = xb[2 * N_ + i0];
        const float ex = xb[i0 + 1], ey = xb[N_ + i0 + 1], ez = xb[2 * N_ + i0 + 1];
        q0 = make_float4(ax, ay, az, ax * ax + ay * ay + az * az);
        q1 = make_float4(ex, ey, ez, ex * ex + ey * ey + ez * ez);
    }
    const float nw0 = -q0.w, nw1 = -q1.w;
    u64 L0 = ~0ull, L1 = ~0ull;
    u32 th0 = 0xFFFFFFFFu, th1 = 0xFFFFFFFFu;
    int cnt0 = 0, cnt1 = 0;

    for (int tile = 0; tile < 4; ++tile) {
        const int tbase = tile << 10;
        __syncthreads();
        for (int t = tid; t < 1024; t += 512) {
            const int g = tbase + t;
            const float cx = xb[g], cy = xb[N_ + g], cz = xb[2 * N_ + g];
            xt[t] = make_float4(cx, cy, cz, cx * cx + cy * cy + cz * cz);
        }
        __syncthreads();
#pragma unroll 2
        for (int it = 0; it < 16; ++it) {
            const int jj = (it << 6) + lane;
            const float4 c = xt[jj];
            const int j = tbase + jj;
            const float dot0 = q0.x * c.x + q0.y * c.y + q0.z * c.z;
            const float dot1 = q1.x * c.x + q1.y * c.y + q1.z * c.z;
            const float d0 = fmaf(dot0, 2.f, nw0) - c.w;   // == 2*dot - xxq - xxj
            const float d1 = fmaf(dot1, 2.f, nw1) - c.w;
            const u32 k0 = fmap(d0), k1 = fmap(d1);
            const bool p0 = (k0 <= th0), p1 = (k1 <= th1);
            const u64 m0 = __ballot(p0), m1 = __ballot(p1);
            if (m0) {
                const int pos = cnt0 + __builtin_amdgcn_mbcnt_hi(
                    (u32)(m0 >> 32), __builtin_amdgcn_mbcnt_lo((u32)m0, 0));
                if (p0) buf[wave][0][pos] = ((u64)k0 << 32) | (u32)j;
                cnt0 += __popcll(m0);
            }
            if (m1) {
                const int pos = cnt1 + __builtin_amdgcn_mbcnt_hi(
                    (u32)(m1 >> 32), __builtin_amdgcn_mbcnt_lo((u32)m1, 0));
                if (p1) buf[wave][1][pos] = ((u64)k1 << 32) | (u32)j;
                cnt1 += __popcll(m1);
            }
            if ((cnt0 | cnt1) >= 64) {        // joint flush, dual sort chains
                const int t0 = min(cnt0, 64), t1 = min(cnt1, 64);
                u64 a = (lane < t0) ? buf[wave][0][cnt0 - t0 + lane] : ~0ull;
                u64 e = (lane < t1) ? buf[wave][1][cnt1 - t1 + lane] : ~0ull;
                sort64_pair(a, e, lane);
                merge_pair(L0, L1, a, e, lane);
                th0 = __shfl((u32)(L0 >> 32), KL - 1);
                th1 = __shfl((u32)(L1 >> 32), KL - 1);
                cnt0 -= t0; cnt1 -= t1;
            }
        }
    }
    if ((cnt0 | cnt1) > 0) {                  // leftovers (< 64 each)
        u64 a = (lane < cnt0) ? buf[wave][0][lane] : ~0ull;
        u64 e = (lane < cnt1) ? buf[wave][1][lane] : ~0ull;
        sort64_pair(a, e, lane);
        merge_pair(L0, L1, a, e, lane);
    }
    if (lane < KL) {
        idx_out[(size_t)((b << 12) + i0) * KL + lane]     = (int)(u32)L0;
        idx_out[(size_t)((b << 12) + i0 + 1) * KL + lane] = (int)(u32)L1;
    }
    // ---- proj epilogue for this block's 16 points ----
    for (int t = tid; t < 16 * 64; t += 512) {
        const int nl = t >> 6, o = t & 63;
        const int n = n0 + nl;
        const float px = xb[n], py = xb[N_ + n], pz = xb[2 * N_ + n];
        const float* ws6 = w_s + o * 6;
        const float* wl6 = w_l + o * 6;
        const size_t gid = (size_t)((b << 12) + n) * 64 + o;
        A_s[gid] = ws6[0] * px + ws6[1] * py + ws6[2] * pz;
        C_s[gid] = (ws6[3] - ws6[0]) * px + (ws6[4] - ws6[1]) * py + (ws6[5] - ws6[2]) * pz;
        A_l[gid] = wl6[0] * px + wl6[1] * py + wl6[2] * pz;
        C_l[gid] = (wl6[3] - wl6[0]) * px + (wl6[4] - wl6[1]) * py + (wl6[5] - wl6[2]) * pz;
    }
}

// ---------------- K3: gather neighbors, per-(b,n) max/min + BN stat partials -----
__global__ __launch_bounds__(256) void gather_kernel(const int* __restrict__ idx,
    const float* __restrict__ A_s, const float* __restrict__ C_s,
    const float* __restrict__ A_l, const float* __restrict__ C_l,
    float* __restrict__ max_s, float* __restrict__ min_s,
    float* __restrict__ max_l, float* __restrict__ min_l,
    float* __restrict__ partial1) {
    const int tid = threadIdx.x;
    const int wave = tid >> 6, lane = tid & 63;
    const int sbid = ((blockIdx.x & 7) << 10) + (blockIdx.x >> 3);  // 1 batch/XCD
    const int bn = sbid * 4 + wave;
    const int b = bn >> 12;
    const int jb = b << 12;
    const int* ip = idx + (size_t)bn * KL;
    const float cs = C_s[(size_t)bn * 64 + lane];
    const float cl = C_l[(size_t)bn * 64 + lane];
    float mxs = -INFINITY, mns = INFINITY, mxl = -INFINITY, mnl = INFINITY;
    float sums = 0.f, sss = 0.f, suml = 0.f, ssl = 0.f;
#pragma unroll
    for (int k = 0; k < KL; ++k) {
        const int j = ip[k];
        const float hl = A_l[(size_t)(jb + j) * 64 + lane] + cl;
        mxl = fmaxf(mxl, hl); mnl = fminf(mnl, hl);
        suml += hl; ssl = fmaf(hl, hl, ssl);
        if (k < KS) {
            const float hs = A_s[(size_t)(jb + j) * 64 + lane] + cs;
            mxs = fmaxf(mxs, hs); mns = fminf(mns, hs);
            sums += hs; sss = fmaf(hs, hs, sss);
        }
    }
    max_s[(size_t)bn * 64 + lane] = mxs; min_s[(size_t)bn * 64 + lane] = mns;
    max_l[(size_t)bn * 64 + lane] = mxl; min_l[(size_t)bn * 64 + lane] = mnl;
    __shared__ float red[4][4][64];
    red[0][wave][lane] = sums; red[1][wave][lane] = sss;
    red[2][wave][lane] = suml; red[3][wave][lane] = ssl;
    __syncthreads();
    const int st = tid >> 6;
    const int o = tid & 63;
    partial1[(size_t)blockIdx.x * 256 + tid] =
        red[st][0][o] + red[st][1][o] + red[st][2][o] + red[st][3][o];
}

// ---------------- K4a/K4b: reduce edge-conv BN stats -> scale/bias ---------------
__global__ void reduce1a_kernel(const float* __restrict__ partial1, double* __restrict__ partialD1) {
    const int t = threadIdx.x;   // 256
    double acc = 0.0;
    const int r0 = blockIdx.x * 64;   // 128 blocks
    for (int r = 0; r < 64; ++r) acc += (double)partial1[(size_t)(r0 + r) * 256 + t];
    partialD1[(size_t)blockIdx.x * 256 + t] = acc;
}

__global__ void reduce1b_kernel(const double* __restrict__ partialD1,
                                const float* __restrict__ g_s, const float* __restrict__ b_s,
                                const float* __restrict__ g_l, const float* __restrict__ b_l,
                                float* __restrict__ sb1) {
    const int t = threadIdx.x;   // 256
    double acc = 0.0;
    for (int r = 0; r < 128; ++r) acc += partialD1[(size_t)r * 256 + t];
    __shared__ double sums[256];
    sums[t] = acc;
    __syncthreads();
    if (t < 64) {
        const double ns = (double)B_ * N_ * KS;
        const double nl = (double)B_ * N_ * KL;
        double mu = sums[t] / ns;
        double var = sums[64 + t] / ns - mu * mu;
        double sc = (double)g_s[t] / sqrt(var + EPSV);
        sb1[t] = (float)sc;
        sb1[64 + t] = (float)((double)b_s[t] - mu * sc);
        mu = sums[128 + t] / nl;
        var = sums[192 + t] / nl - mu * mu;
        sc = (double)g_l[t] / sqrt(var + EPSV);
        sb1[128 + t] = (float)sc;
        sb1[192 + t] = (float)((double)b_l[t] - mu * sc);
    }
}

// ---------------- K5: BN+leaky on maxes, 64x128 fuse matvec, stats ---------------
__global__ __launch_bounds__(256) void fuse_kernel(
    const float* __restrict__ max_s, const float* __restrict__ min_s,
    const float* __restrict__ max_l, const float* __restrict__ min_l,
    const float* __restrict__ sb1, const float* __restrict__ w_f,
    float* __restrict__ f_buf, float* __restrict__ partial2) {
    __shared__ float wfT[128 * 64];   // transposed: wfT[c][o]
    __shared__ float av[4][128];
    __shared__ float red[2][4][64];
    const int tid = threadIdx.x;
    for (int t = tid; t < 8192; t += 256) {
        const int c = t >> 6, o = t & 63;
        wfT[t] = w_f[o * 128 + c];
    }
    const int sbid = ((blockIdx.x & 7) << 8) + (blockIdx.x >> 3);   // 1 batch/XCD
    const int wave = tid >> 6, lane = tid & 63;
    const float sc_s = sb1[lane], bi_s = sb1[64 + lane];
    const float sc_l = sb1[128 + lane], bi_l = sb1[192 + lane];
    float sum_f = 0.f, ss_f = 0.f;
    __syncthreads();
    for (int p = 0; p < 4; ++p) {
        const int bn = (sbid * 4 + wave) * 4 + p;   // 2048 blocks
        const size_t base = (size_t)bn * 64 + lane;
        const float hs = sc_s >= 0.f ? max_s[base] : min_s[base];
        const float a_s = leaky(fmaf(sc_s, hs, bi_s));
        const float hl = sc_l >= 0.f ? max_l[base] : min_l[base];
        const float a_l = leaky(fmaf(sc_l, hl, bi_l));
        av[wave][lane] = a_s;
        av[wave][64 + lane] = a_l;     // per-wave buffer: no block barrier needed
        float acc = 0.f;
#pragma unroll
        for (int c = 0; c < 128; ++c) acc = fmaf(wfT[c * 64 + lane], av[wave][c], acc);
        f_buf[base] = acc;
        sum_f += acc;
        ss_f = fmaf(acc, acc, ss_f);
    }
    red[0][wave][lane] = sum_f;
    red[1][wave][lane] = ss_f;
    __syncthreads();
    if (tid < 128) {
        const int st = tid >> 6, o = tid & 63;
        partial2[(size_t)blockIdx.x * 128 + tid] =
            red[st][0][o] + red[st][1][o] + red[st][2][o] + red[st][3][o];
    }
}

// ---------------- K6a/K6b: reduce final BN stats ---------------------------------
__global__ void reduce2a_kernel(const float* __restrict__ partial2, double* __restrict__ partialD2) {
    const int t = threadIdx.x;   // 128
    double acc = 0.0;
    const int r0 = blockIdx.x * 32;   // 64 blocks
    for (int r = 0; r < 32; ++r) acc += (double)partial2[(size_t)(r0 + r) * 128 + t];
    partialD2[(size_t)blockIdx.x * 128 + t] = acc;
}

__global__ void reduce2b_kernel(const double* __restrict__ partialD2,
                                const float* __restrict__ g_f, const float* __restrict__ b_f,
                                float* __restrict__ sb2) {
    const int t = threadIdx.x;   // 128
    double acc = 0.0;
    for (int r = 0; r < 64; ++r) acc += partialD2[(size_t)r * 128 + t];
    __shared__ double sums[128];
    sums[t] = acc;
    __syncthreads();
    if (t < 64) {
        const double n = (double)B_ * N_;
        const double mu = sums[t] / n;
        const double var = sums[64 + t] / n - mu * mu;
        const double sc = (double)g_f[t] / sqrt(var + EPSV);
        sb2[t] = (float)sc;
        sb2[64 + t] = (float)((double)b_f[t] - mu * sc);
    }
}

// ---------------- K7: final BN+leaky + transpose to [B,O,N] ----------------------
__global__ __launch_bounds__(256) void final_kernel(const float* __restrict__ f_buf,
                                                    const float* __restrict__ sb2,
                                                    float* __restrict__ out) {
    __shared__ float tile[64][65];
    const int sbid = ((blockIdx.x & 7) << 6) + (blockIdx.x >> 3);   // 1 batch/XCD
    const int b = sbid >> 6;                 // 512 blocks
    const int n0 = (sbid & 63) << 6;
#pragma unroll
    for (int r = 0; r < 16; ++r) {
        const int t = r * 256 + threadIdx.x;
        const int n = t >> 6, o = t & 63;
        const float v = f_buf[(size_t)((b << 12) + n0 + n) * 64 + o];
        const float h = fmaf(sb2[o], v, sb2[64 + o]);
        tile[n][o] = leaky(h);
    }
    __syncthreads();
#pragma unroll
    for (int r = 0; r < 16; ++r) {
        const int t = r * 256 + threadIdx.x;
        const int o = t >> 6, n = t & 63;
        out[(size_t)((b << 6) + o) * N_ + n0 + n] = tile[n][o];
    }
}

// ---------------- launch ---------------------------------------------------------
extern "C" void kernel_launch(void* const* d_in, const int* in_sizes, int n_in,
                              void* d_out, int out_size, void* d_ws, size_t ws_size,
                              hipStream_t stream) {
    (void)in_sizes; (void)n_in; (void)out_size; (void)ws_size;
    const float* x   = (const float*)d_in[0];
    const float* w_s = (const float*)d_in[1];
    const float* g_s = (const float*)d_in[2];
    const float* b_s = (const float*)d_in[3];
    const float* w_l = (const float*)d_in[4];
    const float* g_l = (const float*)d_in[5];
    const float* b_l = (const float*)d_in[6];
    const float* w_f = (const float*)d_in[7];
    const float* g_f = (const float*)d_in[8];
    const float* b_f = (const float*)d_in[9];
    float* out = (float*)d_out;
    char* ws = (char*)d_ws;

    constexpr size_t SZ_PT   = (size_t)B_ * N_ * 64 * 4;      // 8,388,608
    constexpr size_t OFF_IDX = 0;
    constexpr size_t OFF_AS  = OFF_IDX + (size_t)B_ * N_ * KL * 4;
    constexpr size_t OFF_CS  = OFF_AS + SZ_PT;
    constexpr size_t OFF_AL  = OFF_CS + SZ_PT;
    constexpr size_t OFF_CL  = OFF_AL + SZ_PT;
    constexpr size_t OFF_MXS = OFF_CL + SZ_PT;
    constexpr size_t OFF_MNS = OFF_MXS + SZ_PT;
    constexpr size_t OFF_MXL = OFF_MNS + SZ_PT;
    constexpr size_t OFF_MNL = OFF_MXL + SZ_PT;
    constexpr size_t OFF_P1  = OFF_MNL + SZ_PT;
    constexpr size_t OFF_PD1 = OFF_P1 + (size_t)8192 * 256 * 4;
    constexpr size_t OFF_SB1 = OFF_PD1 + (size_t)128 * 256 * 8;
    constexpr size_t OFF_F   = OFF_SB1 + 1024;
    constexpr size_t OFF_P2  = OFF_F + SZ_PT;
    constexpr size_t OFF_PD2 = OFF_P2 + (size_t)2048 * 128 * 4;
    constexpr size_t OFF_SB2 = OFF_PD2 + (size_t)64 * 128 * 8;

    int*    idx  = (int*)(ws + OFF_IDX);
    float*  A_s  = (float*)(ws + OFF_AS);
    float*  C_s  = (float*)(ws + OFF_CS);
    float*  A_l  = (float*)(ws + OFF_AL);
    float*  C_l  = (float*)(ws + OFF_CL);
    float*  mxs  = (float*)(ws + OFF_MXS);
    float*  mns  = (float*)(ws + OFF_MNS);
    float*  mxl  = (float*)(ws + OFF_MXL);
    float*  mnl  = (float*)(ws + OFF_MNL);
    float*  p1   = (float*)(ws + OFF_P1);
    double* pd1  = (double*)(ws + OFF_PD1);
    float*  sb1  = (float*)(ws + OFF_SB1);
    float*  fb   = (float*)(ws + OFF_F);
    float*  p2   = (float*)(ws + OFF_P2);
    double* pd2  = (double*)(ws + OFF_PD2);
    float*  sb2  = (float*)(ws + OFF_SB2);

    hipLaunchKernelGGL(knn_kernel, dim3(2048), dim3(512), 0, stream,
                       x, w_s, w_l, idx, A_s, C_s, A_l, C_l);
    hipLaunchKernelGGL(gather_kernel, dim3(8192), dim3(256), 0, stream,
                       idx, A_s, C_s, A_l, C_l, mxs, mns, mxl, mnl, p1);
    hipLaunchKernelGGL(reduce1a_kernel, dim3(128), dim3(256), 0, stream, p1, pd1);
    hipLaunchKernelGGL(reduce1b_kernel, dim3(1), dim3(256), 0, stream, pd1, g_s, b_s, g_l, b_l, sb1);
    hipLaunchKernelGGL(fuse_kernel, dim3(2048), dim3(256), 0, stream,
                       mxs, mns, mxl, mnl, sb1, w_f, fb, p2);
    hipLaunchKernelGGL(reduce2a_kernel, dim3(64), dim3(128), 0, stream, p2, pd2);
    hipLaunchKernelGGL(reduce2b_kernel, dim3(1), dim3(128), 0, stream, pd2, g_f, b_f, sb2);
    hipLaunchKernelGGL(final_kernel, dim3(512), dim3(256), 0, stream, fb, sb2, out);
}

// Round 8
// 216.258 us; speedup vs baseline: 1.2361x; 1.0191x over previous
//
#include <hip/hip_runtime.h>

#define B_ 8
#define N_ 4096
#define O_ 64
#define KL 40
#define KS 20
#define EPSV 1e-5
#define SLOPE 0.2f

typedef unsigned long long u64;
typedef unsigned int u32;

__device__ __forceinline__ float leaky(float v) { return v >= 0.f ? v : SLOPE * v; }

// lane exchange by XOR stride S. S=1,2,8 via DPP (VALU, no LDS); S=4,16,32,63 via
// ds_bpermute with a HOISTED per-lane address (no per-call addr arithmetic).
template <int S>
__device__ __forceinline__ u64 xor_ex64(u64 v, int dsaddr) {
    if constexpr (S == 1 || S == 2 || S == 8) {
        constexpr int CTRL = (S == 1) ? 0xB1 : (S == 2) ? 0x4E : 0x128;
        const int lo = __builtin_amdgcn_update_dpp(0, (int)(u32)v, CTRL, 0xF, 0xF, true);
        const int hi = __builtin_amdgcn_update_dpp(0, (int)(u32)(v >> 32), CTRL, 0xF, 0xF, true);
        return ((u64)(u32)hi << 32) | (u32)lo;
    } else {
        const int lo = __builtin_amdgcn_ds_bpermute(dsaddr, (int)(u32)v);
        const int hi = __builtin_amdgcn_ds_bpermute(dsaddr, (int)(u32)(v >> 32));
        return ((u64)(u32)hi << 32) | (u32)lo;
    }
}

// one bitonic stage (level K, stride S) applied to two independent keys (ILP x2)
template <int K, int S>
__device__ __forceinline__ void stage_pair(u64& a, u64& e, int lane, int dsaddr) {
    const u64 oa = xor_ex64<S>(a, dsaddr);
    const u64 oe = xor_ex64<S>(e, dsaddr);
    const bool sel = (((lane & K) == 0) == ((lane & S) == 0));
    a = ((a < oa) == sel) ? a : oa;
    e = ((e < oe) == sel) ? e : oe;
}

// dual ascending bitonic sort of two independent 64-key sets
__device__ __forceinline__ void sort64_pair(u64& a, u64& e, int lane,
                                            int a4, int a16, int a32) {
    stage_pair<2, 1>(a, e, lane, 0);
    stage_pair<4, 2>(a, e, lane, 0);    stage_pair<4, 1>(a, e, lane, 0);
    stage_pair<8, 4>(a, e, lane, a4);   stage_pair<8, 2>(a, e, lane, 0);    stage_pair<8, 1>(a, e, lane, 0);
    stage_pair<16, 8>(a, e, lane, 0);   stage_pair<16, 4>(a, e, lane, a4);  stage_pair<16, 2>(a, e, lane, 0);   stage_pair<16, 1>(a, e, lane, 0);
    stage_pair<32, 16>(a, e, lane, a16); stage_pair<32, 8>(a, e, lane, 0);  stage_pair<32, 4>(a, e, lane, a4);  stage_pair<32, 2>(a, e, lane, 0);  stage_pair<32, 1>(a, e, lane, 0);
    stage_pair<64, 32>(a, e, lane, a32); stage_pair<64, 16>(a, e, lane, a16); stage_pair<64, 8>(a, e, lane, 0); stage_pair<64, 4>(a, e, lane, a4); stage_pair<64, 2>(a, e, lane, 0); stage_pair<64, 1>(a, e, lane, 0);
}

// L0/L1 ascending lists; a/e ascending buffers. keep 64 smallest of each union.
__device__ __forceinline__ void merge_pair(u64& L0, u64& L1, u64 a, u64 e, int lane,
                                           int a4, int a16, int a32, int a63) {
    const u64 ra = xor_ex64<63>(a, a63);         // reverse -> descending
    const u64 re = xor_ex64<63>(e, a63);
    L0 = (L0 < ra) ? L0 : ra;                    // valley min -> bitonic
    L1 = (L1 < re) ? L1 : re;
    stage_pair<0, 32>(L0, L1, lane, a32);        // K=0 -> pure descending cleanup
    stage_pair<0, 16>(L0, L1, lane, a16);
    stage_pair<0, 8>(L0, L1, lane, 0);
    stage_pair<0, 4>(L0, L1, lane, a4);
    stage_pair<0, 2>(L0, L1, lane, 0);
    stage_pair<0, 1>(L0, L1, lane, 0);
}

// ---------------- K1: KNN (2 queries/wave, 1K-pt tiles, joint dual flush) --------
__global__ __launch_bounds__(512, 8) void knn_kernel(const float* __restrict__ x,
                                                     const float* __restrict__ w_s,
                                                     const float* __restrict__ w_l,
                                                     int* __restrict__ idx_out,
                                                     float* __restrict__ A_s,
                                                     float* __restrict__ C_s,
                                                     float* __restrict__ A_l,
                                                     float* __restrict__ C_l) {
    __shared__ float4 xt[1024];         // 16 KB point tile (x,y,z,xx)
    __shared__ u64 buf[8][2][128];      // 16 KB candidate buffers
    const int sbid = ((blockIdx.x & 7) << 8) + (blockIdx.x >> 3);  // XCD: 1 batch/XCD
    const int b = sbid >> 8;
    const int n0 = (sbid & 255) << 4;   // 16 queries per block
    const float* xb = x + (size_t)b * 3 * N_;
    const int tid = threadIdx.x;
    const int wave = tid >> 6, lane = tid & 63;
    const int i0 = n0 + wave * 2;
    // hoisted bpermute byte-addresses for the sort/merge lane exchanges
    const int a4 = (lane ^ 4) << 2, a16 = (lane ^ 16) << 2;
    const int a32 = (lane ^ 32) << 2, a63 = (lane ^ 63) << 2;

    float4 q0, q1;
    {
        const float ax = xb[i0],     ay = xb[N_ + i0],     az = xb[2 * N_ + i0];
        const float ex = xb[i0 + 1], ey = xb[N_ + i0 + 1], ez = xb[2 * N_ + i0 + 1];
        q0 = make_float4(ax, ay, az, ax * ax + ay * ay + az * az);
        q1 = make_float4(ex, ey, ez, ex * ex + ey * ey + ez * ez);
    }
    const float nw0 = -q0.w, nw1 = -q1.w;
    u64 L0 = ~0ull, L1 = ~0ull;
    float th0 = -INFINITY, th1 = -INFINITY;   // rank-39 float threshold (uniform)
    int cnt0 = 0, cnt1 = 0;

    for (int tile = 0; tile < 4; ++tile) {
        const int tbase = tile << 10;
        __syncthreads();
        for (int t = tid; t < 1024; t += 512) {
            const int g = tbase + t;
            const float cx = xb[g], cy = xb[N_ + g], cz = xb[2 * N_ + g];
            xt[t] = make_float4(cx, cy, cz, cx * cx + cy * cy + cz * cz);
        }
        __syncthreads();
#pragma unroll 4
        for (int it = 0; it < 16; ++it) {
            const int jj = (it << 6) + lane;
            const float4 c = xt[jj];
            const int j = tbase + jj;
            const float dot0 = q0.x * c.x + q0.y * c.y + q0.z * c.z;
            const float dot1 = q1.x * c.x + q1.y * c.y + q1.z * c.z;
            const float d0 = fmaf(dot0, 2.f, nw0) - c.w;   // == 2*dot - xxq - xxj
            const float d1 = fmaf(dot1, 2.f, nw1) - c.w;
            // accept set identical to u64 hi-word compare: d > thr, plus all d == thr
            const bool p0 = (d0 >= th0);
            const bool p1 = (d1 >= th1);
            const u64 m0 = __ballot(p0), m1 = __ballot(p1);
            if (m0) {
                const int pos = cnt0 + __builtin_amdgcn_mbcnt_hi(
                    (u32)(m0 >> 32), __builtin_amdgcn_mbcnt_lo((u32)m0, 0));
                if (p0) {
                    const u32 k0 = __float_as_uint(fminf(d0, -0.0f));
                    buf[wave][0][pos] = ((u64)k0 << 32) | (u32)j;
                }
                cnt0 += __popcll(m0);
            }
            if (m1) {
                const int pos = cnt1 + __builtin_amdgcn_mbcnt_hi(
                    (u32)(m1 >> 32), __builtin_amdgcn_mbcnt_lo((u32)m1, 0));
                if (p1) {
                    const u32 k1 = __float_as_uint(fminf(d1, -0.0f));
                    buf[wave][1][pos] = ((u64)k1 << 32) | (u32)j;
                }
                cnt1 += __popcll(m1);
            }
            if ((cnt0 | cnt1) >= 64) {        // joint flush, dual sort chains
                const int t0 = min(cnt0, 64), t1 = min(cnt1, 64);
                u64 a = (lane < t0) ? buf[wave][0][cnt0 - t0 + lane] : ~0ull;
                u64 e = (lane < t1) ? buf[wave][1][cnt1 - t1 + lane] : ~0ull;
                sort64_pair(a, e, lane, a4, a16, a32);
                merge_pair(L0, L1, a, e, lane, a4, a16, a32, a63);
                // keys are negative-float bit patterns -> unfmap is identity
                th0 = __uint_as_float((u32)__builtin_amdgcn_readlane((int)(u32)(L0 >> 32), KL - 1));
                th1 = __uint_as_float((u32)__builtin_amdgcn_readlane((int)(u32)(L1 >> 32), KL - 1));
                cnt0 -= t0; cnt1 -= t1;
            }
        }
    }
    if ((cnt0 | cnt1) > 0) {                  // leftovers (< 64 each)
        u64 a = (lane < cnt0) ? buf[wave][0][lane] : ~0ull;
        u64 e = (lane < cnt1) ? buf[wave][1][lane] : ~0ull;
        sort64_pair(a, e, lane, a4, a16, a32);
        merge_pair(L0, L1, a, e, lane, a4, a16, a32, a63);
    }
    if (lane < KL) {
        idx_out[(size_t)((b << 12) + i0) * KL + lane]     = (int)(u32)L0;
        idx_out[(size_t)((b << 12) + i0 + 1) * KL + lane] = (int)(u32)L1;
    }
    // ---- proj epilogue for this block's 16 points ----
    for (int t = tid; t < 16 * 64; t += 512) {
        const int nl = t >> 6, o = t & 63;
        const int n = n0 + nl;
        const float px = xb[n], py = xb[N_ + n], pz = xb[2 * N_ + n];
        const float* ws6 = w_s + o * 6;
        const float* wl6 = w_l + o * 6;
        const size_t gid = (size_t)((b << 12) + n) * 64 + o;
        A_s[gid] = ws6[0] * px + ws6[1] * py + ws6[2] * pz;
        C_s[gid] = (ws6[3] - ws6[0]) * px + (ws6[4] - ws6[1]) * py + (ws6[5] - ws6[2]) * pz;
        A_l[gid] = wl6[0] * px + wl6[1] * py + wl6[2] * pz;
        C_l[gid] = (wl6[3] - wl6[0]) * px + (wl6[4] - wl6[1]) * py + (wl6[5] - wl6[2]) * pz;
    }
}

// ---------------- K3: gather neighbors, per-(b,n) max/min + BN stat partials -----
__global__ __launch_bounds__(256) void gather_kernel(const int* __restrict__ idx,
    const float* __restrict__ A_s, const float* __restrict__ C_s,
    const float* __restrict__ A_l, const float* __restrict__ C_l,
    float* __restrict__ max_s, float* __restrict__ min_s,
    float* __restrict__ max_l, float* __restrict__ min_l,
    float* __restrict__ partial1) {
    const int tid = threadIdx.x;
    const int wave = tid >> 6, lane = tid & 63;
    const int sbid = ((blockIdx.x & 7) << 10) + (blockIdx.x >> 3);  // 1 batch/XCD
    const int bn = sbid * 4 + wave;
    const int b = bn >> 12;
    const int jb = b << 12;
    const int* ip = idx + (size_t)bn * KL;
    const float cs = C_s[(size_t)bn * 64 + lane];
    const float cl = C_l[(size_t)bn * 64 + lane];
    float mxs = -INFINITY, mns = INFINITY, mxl = -INFINITY, mnl = INFINITY;
    float sums = 0.f, sss = 0.f, suml = 0.f, ssl = 0.f;
#pragma unroll
    for (int k = 0; k < KL; ++k) {
        const int j = ip[k];
        const float hl = A_l[(size_t)(jb + j) * 64 + lane] + cl;
        mxl = fmaxf(mxl, hl); mnl = fminf(mnl, hl);
        suml += hl; ssl = fmaf(hl, hl, ssl);
        if (k < KS) {
            const float hs = A_s[(size_t)(jb + j) * 64 + lane] + cs;
            mxs = fmaxf(mxs, hs); mns = fminf(mns, hs);
            sums += hs; sss = fmaf(hs, hs, sss);
        }
    }
    max_s[(size_t)bn * 64 + lane] = mxs; min_s[(size_t)bn * 64 + lane] = mns;
    max_l[(size_t)bn * 64 + lane] = mxl; min_l[(size_t)bn * 64 + lane] = mnl;
    __shared__ float red[4][4][64];
    red[0][wave][lane] = sums; red[1][wave][lane] = sss;
    red[2][wave][lane] = suml; red[3][wave][lane] = ssl;
    __syncthreads();
    const int st = tid >> 6;
    const int o = tid & 63;
    partial1[(size_t)blockIdx.x * 256 + tid] =
        red[st][0][o] + red[st][1][o] + red[st][2][o] + red[st][3][o];
}

// ---------------- K4a/K4b: reduce edge-conv BN stats -> scale/bias ---------------
__global__ void reduce1a_kernel(const float* __restrict__ partial1, double* __restrict__ partialD1) {
    const int t = threadIdx.x;   // 256
    double acc = 0.0;
    const int r0 = blockIdx.x * 64;   // 128 blocks
    for (int r = 0; r < 64; ++r) acc += (double)partial1[(size_t)(r0 + r) * 256 + t];
    partialD1[(size_t)blockIdx.x * 256 + t] = acc;
}

__global__ void reduce1b_kernel(const double* __restrict__ partialD1,
                                const float* __restrict__ g_s, const float* __restrict__ b_s,
                                const float* __restrict__ g_l, const float* __restrict__ b_l,
                                float* __restrict__ sb1) {
    const int t = threadIdx.x;   // 256
    double acc = 0.0;
    for (int r = 0; r < 128; ++r) acc += partialD1[(size_t)r * 256 + t];
    __shared__ double sums[256];
    sums[t] = acc;
    __syncthreads();
    if (t < 64) {
        const double ns = (double)B_ * N_ * KS;
        const double nl = (double)B_ * N_ * KL;
        double mu = sums[t] / ns;
        double var = sums[64 + t] / ns - mu * mu;
        double sc = (double)g_s[t] / sqrt(var + EPSV);
        sb1[t] = (float)sc;
        sb1[64 + t] = (float)((double)b_s[t] - mu * sc);
        mu = sums[128 + t] / nl;
        var = sums[192 + t] / nl - mu * mu;
        sc = (double)g_l[t] / sqrt(var + EPSV);
        sb1[128 + t] = (float)sc;
        sb1[192 + t] = (float)((double)b_l[t] - mu * sc);
    }
}

// ---------------- K5: BN+leaky on maxes, 64x128 fuse matvec, stats ---------------
__global__ __launch_bounds__(256) void fuse_kernel(
    const float* __restrict__ max_s, const float* __restrict__ min_s,
    const float* __restrict__ max_l, const float* __restrict__ min_l,
    const float* __restrict__ sb1, const float* __restrict__ w_f,
    float* __restrict__ f_buf, float* __restrict__ partial2) {
    __shared__ float wfT[128 * 64];   // transposed: wfT[c][o]
    __shared__ float av[4][128];
    __shared__ float red[2][4][64];
    const int tid = threadIdx.x;
    for (int t = tid; t < 8192; t += 256) {
        const int c = t >> 6, o = t & 63;
        wfT[t] = w_f[o * 128 + c];
    }
    const int sbid = ((blockIdx.x & 7) << 8) + (blockIdx.x >> 3);   // 1 batch/XCD
    const int wave = tid >> 6, lane = tid & 63;
    const float sc_s = sb1[lane], bi_s = sb1[64 + lane];
    const float sc_l = sb1[128 + lane], bi_l = sb1[192 + lane];
    float sum_f = 0.f, ss_f = 0.f;
    __syncthreads();
    for (int p = 0; p < 4; ++p) {
        const int bn = (sbid * 4 + wave) * 4 + p;   // 2048 blocks
        const size_t base = (size_t)bn * 64 + lane;
        const float hs = sc_s >= 0.f ? max_s[base] : min_s[base];
        const float a_s = leaky(fmaf(sc_s, hs, bi_s));
        const float hl = sc_l >= 0.f ? max_l[base] : min_l[base];
        const float a_l = leaky(fmaf(sc_l, hl, bi_l));
        av[wave][lane] = a_s;
        av[wave][64 + lane] = a_l;     // per-wave buffer: no block barrier needed
        float acc = 0.f;
#pragma unroll
        for (int c = 0; c < 128; ++c) acc = fmaf(wfT[c * 64 + lane], av[wave][c], acc);
        f_buf[base] = acc;
        sum_f += acc;
        ss_f = fmaf(acc, acc, ss_f);
    }
    red[0][wave][lane] = sum_f;
    red[1][wave][lane] = ss_f;
    __syncthreads();
    if (tid < 128) {
        const int st = tid >> 6, o = tid & 63;
        partial2[(size_t)blockIdx.x * 128 + tid] =
            red[st][0][o] + red[st][1][o] + red[st][2][o] + red[st][3][o];
    }
}

// ---------------- K6a/K6b: reduce final BN stats ---------------------------------
__global__ void reduce2a_kernel(const float* __restrict__ partial2, double* __restrict__ partialD2) {
    const int t = threadIdx.x;   // 128
    double acc = 0.0;
    const int r0 = blockIdx.x * 32;   // 64 blocks
    for (int r = 0; r < 32; ++r) acc += (double)partial2[(size_t)(r0 + r) * 128 + t];
    partialD2[(size_t)blockIdx.x * 128 + t] = acc;
}

__global__ void reduce2b_kernel(const double* __restrict__ partialD2,
                                const float* __restrict__ g_f, const float* __restrict__ b_f,
                                float* __restrict__ sb2) {
    const int t = threadIdx.x;   // 128
    double acc = 0.0;
    for (int r = 0; r < 64; ++r) acc += partialD2[(size_t)r * 128 + t];
    __shared__ double sums[128];
    sums[t] = acc;
    __syncthreads();
    if (t < 64) {
        const double n = (double)B_ * N_;
        const double mu = sums[t] / n;
        const double var = sums[64 + t] / n - mu * mu;
        const double sc = (double)g_f[t] / sqrt(var + EPSV);
        sb2[t] = (float)sc;
        sb2[64 + t] = (float)((double)b_f[t] - mu * sc);
    }
}

// ---------------- K7: final BN+leaky + transpose to [B,O,N] ----------------------
__global__ __launch_bounds__(256) void final_kernel(const float* __restrict__ f_buf,
                                                    const float* __restrict__ sb2,
                                                    float* __restrict__ out) {
    __shared__ float tile[64][65];
    const int sbid = ((blockIdx.x & 7) << 6) + (blockIdx.x >> 3);   // 1 batch/XCD
    const int b = sbid >> 6;                 // 512 blocks
    const int n0 = (sbid & 63) << 6;
#pragma unroll
    for (int r = 0; r < 16; ++r) {
        const int t = r * 256 + threadIdx.x;
        const int n = t >> 6, o = t & 63;
        const float v = f_buf[(size_t)((b << 12) + n0 + n) * 64 + o];
        const float h = fmaf(sb2[o], v, sb2[64 + o]);
        tile[n][o] = leaky(h);
    }
    __syncthreads();
#pragma unroll
    for (int r = 0; r < 16; ++r) {
        const int t = r * 256 + threadIdx.x;
        const int o = t >> 6, n = t & 63;
        out[(size_t)((b << 6) + o) * N_ + n0 + n] = tile[n][o];
    }
}

// ---------------- launch ---------------------------------------------------------
extern "C" void kernel_launch(void* const* d_in, const int* in_sizes, int n_in,
                              void* d_out, int out_size, void* d_ws, size_t ws_size,
                              hipStream_t stream) {
    (void)in_sizes; (void)n_in; (void)out_size; (void)ws_size;
    const float* x   = (const float*)d_in[0];
    const float* w_s = (const float*)d_in[1];
    const float* g_s = (const float*)d_in[2];
    const float* b_s = (const float*)d_in[3];
    const float* w_l = (const float*)d_in[4];
    const float* g_l = (const float*)d_in[5];
    const float* b_l = (const float*)d_in[6];
    const float* w_f = (const float*)d_in[7];
    const float* g_f = (const float*)d_in[8];
    const float* b_f = (const float*)d_in[9];
    float* out = (float*)d_out;
    char* ws = (char*)d_ws;

    constexpr size_t SZ_PT   = (size_t)B_ * N_ * 64 * 4;      // 8,388,608
    constexpr size_t OFF_IDX = 0;
    constexpr size_t OFF_AS  = OFF_IDX + (size_t)B_ * N_ * KL * 4;
    constexpr size_t OFF_CS  = OFF_AS + SZ_PT;
    constexpr size_t OFF_AL  = OFF_CS + SZ_PT;
    constexpr size_t OFF_CL  = OFF_AL + SZ_PT;
    constexpr size_t OFF_MXS = OFF_CL + SZ_PT;
    constexpr size_t OFF_MNS = OFF_MXS + SZ_PT;
    constexpr size_t OFF_MXL = OFF_MNS + SZ_PT;
    constexpr size_t OFF_MNL = OFF_MXL + SZ_PT;
    constexpr size_t OFF_P1  = OFF_MNL + SZ_PT;
    constexpr size_t OFF_PD1 = OFF_P1 + (size_t)8192 * 256 * 4;
    constexpr size_t OFF_SB1 = OFF_PD1 + (size_t)128 * 256 * 8;
    constexpr size_t OFF_F   = OFF_SB1 + 1024;
    constexpr size_t OFF_P2  = OFF_F + SZ_PT;
    constexpr size_t OFF_PD2 = OFF_P2 + (size_t)2048 * 128 * 4;
    constexpr size_t OFF_SB2 = OFF_PD2 + (size_t)64 * 128 * 8;

    int*    idx  = (int*)(ws + OFF_IDX);
    float*  A_s  = (float*)(ws + OFF_AS);
    float*  C_s  = (float*)(ws + OFF_CS);
    float*  A_l  = (float*)(ws + OFF_AL);
    float*  C_l  = (float*)(ws + OFF_CL);
    float*  mxs  = (float*)(ws + OFF_MXS);
    float*  mns  = (float*)(ws + OFF_MNS);
    float*  mxl  = (float*)(ws + OFF_MXL);
    float*  mnl  = (float*)(ws + OFF_MNL);
    float*  p1   = (float*)(ws + OFF_P1);
    double* pd1  = (double*)(ws + OFF_PD1);
    float*  sb1  = (float*)(ws + OFF_SB1);
    float*  fb   = (float*)(ws + OFF_F);
    float*  p2   = (float*)(ws + OFF_P2);
    double* pd2  = (double*)(ws + OFF_PD2);
    float*  sb2  = (float*)(ws + OFF_SB2);

    hipLaunchKernelGGL(knn_kernel, dim3(2048), dim3(512), 0, stream,
                       x, w_s, w_l, idx, A_s, C_s, A_l, C_l);
    hipLaunchKernelGGL(gather_kernel, dim3(8192), dim3(256), 0, stream,
                       idx, A_s, C_s, A_l, C_l, mxs, mns, mxl, mnl, p1);
    hipLaunchKernelGGL(reduce1a_kernel, dim3(128), dim3(256), 0, stream, p1, pd1);
    hipLaunchKernelGGL(reduce1b_kernel, dim3(1), dim3(256), 0, stream, pd1, g_s, b_s, g_l, b_l, sb1);
    hipLaunchKernelGGL(fuse_kernel, dim3(2048), dim3(256), 0, stream,
                       mxs, mns, mxl, mnl, sb1, w_f, fb, p2);
    hipLaunchKernelGGL(reduce2a_kernel, dim3(64), dim3(128), 0, stream, p2, pd2);
    hipLaunchKernelGGL(reduce2b_kernel, dim3(1), dim3(128), 0, stream, pd2, g_f, b_f, sb2);
    hipLaunchKernelGGL(final_kernel, dim3(512), dim3(256), 0, stream, fb, sb2, out);
}